// Round 4
// baseline (1166.876 us; speedup 1.0000x reference)
//
#include <hip/hip_runtime.h>
#include <cstdint>
#include <cstddef>

#define S_ROWS 4096
#define DIM 1024
#define NE 64
#define CAP 512
#define NEGV -1e9f
#define NGEMM 128           // gemm+gating blocks, 32 rows each
#define NFB 65536           // one-shot fill blocks
#define N4 67108864LL       // (2*S*NE*CAP)/4 v4f elements; == 4 * NFB * 256

typedef float v4f __attribute__((ext_vector_type(4)));

// ---------------- kernel F: rocclr-shaped zero fill: one-shot blocks, no LDS, tiny VGPR --------
__global__ __launch_bounds__(256) void fillZ(v4f* __restrict__ out4, float* __restrict__ out,
                                             long long n) {
    const long long T = (long long)NFB * 256;          // 16,777,216 v4f per sweep
    const long long i = (long long)blockIdx.x * 256 + threadIdx.x;
    v4f z = {0.f, 0.f, 0.f, 0.f};
    __builtin_nontemporal_store(z, &out4[i]);
    __builtin_nontemporal_store(z, &out4[i + T]);
    __builtin_nontemporal_store(z, &out4[i + 2 * T]);
    __builtin_nontemporal_store(z, &out4[i + 3 * T]);
    if (blockIdx.x == 0 && threadIdx.x == 0)
        for (long long j = N4 * 4; j < n; ++j) out[j] = 0.f;   // 1 tail element
}

// ---------------- kernel A: fused gemm (both matrices) + gating --------------------------------
__global__ __launch_bounds__(256) void gateA(const float* __restrict__ X1, const float* __restrict__ W1,
                                             const float* __restrict__ X2, const float* __restrict__ W2,
                                             int* __restrict__ eidx, float* __restrict__ gval,
                                             float* __restrict__ Gslot, int* __restrict__ Cslot) {
    const int bid = blockIdx.x;
    const int tid = threadIdx.x;

    __shared__ float As[32][68];      // [row][k], +4 pad
    __shared__ float Bs[64][68];      // [k][expert]
    __shared__ float Lg[2][32][68];   // logits of both matrices, block-local rows
    __shared__ float sG[4][NE];
    __shared__ int   hist[NE];

    if (tid < NE) hist[tid] = 0;

    const int row0 = bid * 32;
    const int tx = tid & 15;          // expert quad
    const int ty = tid >> 4;          // row pair

    #pragma unroll
    for (int m = 0; m < 2; ++m) {
        const float* __restrict__ X = m ? X2 : X1;
        const float* __restrict__ W = m ? W2 : W1;
        float acc[2][4] = {};
        for (int kk = 0; kk < DIM; kk += 64) {
            __syncthreads();
            #pragma unroll
            for (int p = 0; p < 2; ++p) {
                int r  = ty + p * 16;
                int c4 = tx * 4;
                float4 a = *(const float4*)&X[(size_t)(row0 + r) * DIM + kk + c4];
                *(float4*)&As[r][c4] = a;
            }
            #pragma unroll
            for (int p = 0; p < 4; ++p) {
                int e  = ty + p * 16;
                int c4 = tx * 4;
                float4 w = *(const float4*)&W[(size_t)e * DIM + kk + c4];
                Bs[c4 + 0][e] = w.x;
                Bs[c4 + 1][e] = w.y;
                Bs[c4 + 2][e] = w.z;
                Bs[c4 + 3][e] = w.w;
            }
            __syncthreads();
            #pragma unroll
            for (int k4 = 0; k4 < 64; k4 += 4) {
                float4 a[2], b[4];
                #pragma unroll
                for (int i = 0; i < 2; ++i) a[i] = *(float4*)&As[ty * 2 + i][k4];
                #pragma unroll
                for (int t = 0; t < 4; ++t) b[t] = *(float4*)&Bs[k4 + t][tx * 4];
                #pragma unroll
                for (int i = 0; i < 2; ++i) {
                    acc[i][0] += a[i].x * b[0].x + a[i].y * b[1].x + a[i].z * b[2].x + a[i].w * b[3].x;
                    acc[i][1] += a[i].x * b[0].y + a[i].y * b[1].y + a[i].z * b[2].y + a[i].w * b[3].y;
                    acc[i][2] += a[i].x * b[0].z + a[i].y * b[1].z + a[i].z * b[2].z + a[i].w * b[3].z;
                    acc[i][3] += a[i].x * b[0].w + a[i].y * b[1].w + a[i].z * b[2].w + a[i].w * b[3].w;
                }
            }
        }
        #pragma unroll
        for (int i = 0; i < 2; ++i)
            #pragma unroll
            for (int t = 0; t < 4; ++t)
                Lg[m][ty * 2 + i][tx * 4 + t] = acc[i][t];
    }
    __syncthreads();   // logits of both matrices visible; hist init visible

    // gating: wave w handles local rows w*8 .. w*8+7 ; lane = expert
    const int wid = tid >> 6, lane = tid & 63;
    float gacc = 0.f;
    #pragma unroll
    for (int i = 0; i < 8; ++i) {
        const int lr = wid * 8 + i;
        const int r  = row0 + lr;
        float l1 = Lg[0][lr][lane];
        if (lane == 0) l1 = NEGV;                 // group 0 excluded before softmax

        // rank under (value desc, index asc) -> top-16 set == jax.lax.top_k set
        int cnt = 0;
        #pragma unroll
        for (int j = 0; j < 64; ++j) {
            float vj = __shfl(l1, j);
            cnt += (vj > l1 || (vj == l1 && j < lane));
        }
        const bool sel = cnt < 16;

        float l2 = Lg[1][lr][lane];
        float ml = sel ? l2 : NEGV;

        float mx = ml;
        #pragma unroll
        for (int o = 32; o; o >>= 1) mx = fmaxf(mx, __shfl_xor(mx, o));
        float ex = expf(ml - mx);                 // unselected underflow to exact 0
        float sum = ex;
        #pragma unroll
        for (int o = 32; o; o >>= 1) sum += __shfl_xor(sum, o);
        float g = ex / sum;
        gacc += g;

        // argmax, lowest-index tie-break (softmax monotone -> matches ref)
        float bg = g; int bi = lane;
        #pragma unroll
        for (int o = 32; o; o >>= 1) {
            float og = __shfl_xor(bg, o);
            int   oi = __shfl_xor(bi, o);
            if (og > bg || (og == bg && oi < bi)) { bg = og; bi = oi; }
        }
        if (lane == 0) {
            eidx[r] = bi;
            gval[r] = bg;
            atomicAdd(&hist[bi], 1);
        }
    }
    sG[wid][lane] = gacc;
    __syncthreads();
    if (tid < NE) {
        Gslot[bid * NE + tid] = sG[0][tid] + sG[1][tid] + sG[2][tid] + sG[3][tid];
        Cslot[bid * NE + tid] = hist[tid];
    }
}

// ---------------- kernel B: 17 blocks. 0..15 = rank via histograms + direct scatter; 16 = l_aux -
__global__ __launch_bounds__(256) void finishC(const int* __restrict__ eidx, const float* __restrict__ gval,
                                               const float* __restrict__ Gslot, const int* __restrict__ Cslot,
                                               float* __restrict__ out) {
    const int bid = blockIdx.x;
    const int tid = threadIdx.x;

    if (bid == 16) {
        if (tid < NE) {
            const int e = tid;
            float Ge = 0.f; int Ce = 0;
            for (int b = 0; b < NGEMM; ++b) {
                Ge += Gslot[b * NE + e];
                Ce += Cslot[b * NE + e];
            }
            float v = Ge * (float)Ce;
            #pragma unroll
            for (int o = 32; o; o >>= 1) v += __shfl_xor(v, o);
            // l_aux = sum_e G_e*C_e / (S*S) * (E*E/num_2nd) = sum/65536
            if (e == 0) out[0] = v * (1.0f / 65536.0f);
        }
        return;
    }

    __shared__ int Cs[NGEMM * NE];    // 32 KB: per-32-row-block expert histograms
    __shared__ int Es[256];           // this block's 256 expert indices
    for (int t = tid; t < NGEMM * NE; t += 256) Cs[t] = Cslot[t];
    const int s = bid * 256 + tid;
    Es[tid] = eidx[s];
    __syncthreads();

    const int e  = Es[tid];
    const int b0 = s >> 5;            // global 32-row block index of s
    int rank = 0;
    for (int b = 0; b < b0; ++b) rank += Cs[b * NE + e];
    for (int jl = (tid & ~31); jl < tid; ++jl) rank += (Es[jl] == e);

    if (rank < CAP) {
        size_t base = 1 + (((size_t)s * NE + e) * CAP + (size_t)rank);
        out[base] = gval[s];                                  // combine
        out[base + (size_t)S_ROWS * NE * CAP] = 1.0f;         // dispatch
    }
}

extern "C" void kernel_launch(void* const* d_in, const int* in_sizes, int n_in,
                              void* d_out, int out_size, void* d_ws, size_t ws_size,
                              hipStream_t stream) {
    const float* in1 = (const float*)d_in[0];
    const float* in2 = (const float*)d_in[1];
    const float* wg1 = (const float*)d_in[2];
    const float* wg2 = (const float*)d_in[3];
    float* out = (float*)d_out;

    int*   eidx  = (int*)d_ws;                          // [4096]
    float* gv    = (float*)(eidx + S_ROWS);             // [4096]
    float* Gslot = gv + S_ROWS;                         // [128*64]
    int*   Cslot = (int*)(Gslot + NGEMM * NE);          // [128*64]

    long long n = (long long)out_size;

    fillZ<<<NFB, 256, 0, stream>>>((v4f*)out, out, n);
    gateA<<<NGEMM, 256, 0, stream>>>(in1, wg1, in2, wg2, eidx, gv, Gslot, Cslot);
    finishC<<<17, 256, 0, stream>>>(eidx, gv, Gslot, Cslot, out);
}

// Round 5
// 1074.588 us; speedup vs baseline: 1.0859x; 1.0859x over previous
//
#include <hip/hip_runtime.h>
#include <cstdint>
#include <cstddef>

#define S_ROWS 4096
#define DIM 1024
#define NE 64
#define CAP 512
#define NEGV -1e9f
#define NGEMM 128           // fused gemm+gating blocks, 32 rows each
#define NFILL 4096          // zero-fill blocks (grid-stride, best-measured config R0)

typedef float v4f __attribute__((ext_vector_type(4)));

// ---------------- kernel A: zero-fill (blocks >= NGEMM) + fused gemm+gating (blocks < NGEMM) ----
// d_out writes are buffer-capped at ~3 TB/s (measured across 4 fill variants incl. rocclr's own
// fill via hipMemsetAsync); the nt grid-stride fill below was the fastest observed, and the gemm
// runs on the other CUs entirely hidden under it.
__global__ __launch_bounds__(256) void fusedA(const float* __restrict__ X1, const float* __restrict__ W1,
                                              const float* __restrict__ X2, const float* __restrict__ W2,
                                              int* __restrict__ eidx, float* __restrict__ gval,
                                              float* __restrict__ Gslot, int* __restrict__ Cslot,
                                              v4f* __restrict__ out4, long long n4,
                                              float* __restrict__ out, long long n) {
    const int bid = blockIdx.x;
    const int tid = threadIdx.x;

    __shared__ float As[32][68];      // [row][k], +4 pad
    __shared__ float Bs[64][68];      // [k][expert]
    __shared__ float Lg[2][32][68];   // logits of both matrices, block-local rows
    __shared__ float sG[4][NE];
    __shared__ int   hist[NE];

    if (bid >= NGEMM) {
        // ---- streaming zero-fill of d_out (nt stores: best-measured, R0) ----
        long long i = (long long)(bid - NGEMM) * 256 + tid;
        const long long stride = (long long)(gridDim.x - NGEMM) * 256;
        v4f z = {0.f, 0.f, 0.f, 0.f};
        for (; i < n4; i += stride) __builtin_nontemporal_store(z, &out4[i]);
        if (bid == NGEMM && tid == 0)
            for (long long j = n4 * 4; j < n; ++j) out[j] = 0.f;   // 1 tail element
        return;
    }

    // ---- fused gemm (both matrices) + gating for rows [bid*32, bid*32+32) ----
    if (tid < NE) hist[tid] = 0;

    const int row0 = bid * 32;
    const int tx = tid & 15;          // expert quad
    const int ty = tid >> 4;          // row pair

    #pragma unroll
    for (int m = 0; m < 2; ++m) {
        const float* __restrict__ X = m ? X2 : X1;
        const float* __restrict__ W = m ? W2 : W1;
        float acc[2][4] = {};
        for (int kk = 0; kk < DIM; kk += 64) {
            __syncthreads();
            #pragma unroll
            for (int p = 0; p < 2; ++p) {
                int r  = ty + p * 16;
                int c4 = tx * 4;
                float4 a = *(const float4*)&X[(size_t)(row0 + r) * DIM + kk + c4];
                *(float4*)&As[r][c4] = a;
            }
            #pragma unroll
            for (int p = 0; p < 4; ++p) {
                int e  = ty + p * 16;
                int c4 = tx * 4;
                float4 w = *(const float4*)&W[(size_t)e * DIM + kk + c4];
                Bs[c4 + 0][e] = w.x;
                Bs[c4 + 1][e] = w.y;
                Bs[c4 + 2][e] = w.z;
                Bs[c4 + 3][e] = w.w;
            }
            __syncthreads();
            #pragma unroll
            for (int k4 = 0; k4 < 64; k4 += 4) {
                float4 a[2], b[4];
                #pragma unroll
                for (int i = 0; i < 2; ++i) a[i] = *(float4*)&As[ty * 2 + i][k4];
                #pragma unroll
                for (int t = 0; t < 4; ++t) b[t] = *(float4*)&Bs[k4 + t][tx * 4];
                #pragma unroll
                for (int i = 0; i < 2; ++i) {
                    acc[i][0] += a[i].x * b[0].x + a[i].y * b[1].x + a[i].z * b[2].x + a[i].w * b[3].x;
                    acc[i][1] += a[i].x * b[0].y + a[i].y * b[1].y + a[i].z * b[2].y + a[i].w * b[3].y;
                    acc[i][2] += a[i].x * b[0].z + a[i].y * b[1].z + a[i].z * b[2].z + a[i].w * b[3].z;
                    acc[i][3] += a[i].x * b[0].w + a[i].y * b[1].w + a[i].z * b[2].w + a[i].w * b[3].w;
                }
            }
        }
        #pragma unroll
        for (int i = 0; i < 2; ++i)
            #pragma unroll
            for (int t = 0; t < 4; ++t)
                Lg[m][ty * 2 + i][tx * 4 + t] = acc[i][t];
    }
    __syncthreads();   // logits of both matrices visible; hist init visible

    // gating: wave w handles local rows w*8 .. w*8+7 ; lane = expert
    const int wid = tid >> 6, lane = tid & 63;
    float gacc = 0.f;
    #pragma unroll
    for (int i = 0; i < 8; ++i) {
        const int lr = wid * 8 + i;
        const int r  = row0 + lr;
        float l1 = Lg[0][lr][lane];
        if (lane == 0) l1 = NEGV;                 // group 0 excluded before softmax

        // rank under (value desc, index asc) -> top-16 set == jax.lax.top_k set
        int cnt = 0;
        #pragma unroll
        for (int j = 0; j < 64; ++j) {
            float vj = __shfl(l1, j);
            cnt += (vj > l1 || (vj == l1 && j < lane));
        }
        const bool sel = cnt < 16;

        float l2 = Lg[1][lr][lane];
        float ml = sel ? l2 : NEGV;

        float mx = ml;
        #pragma unroll
        for (int o = 32; o; o >>= 1) mx = fmaxf(mx, __shfl_xor(mx, o));
        float ex = expf(ml - mx);                 // unselected underflow to exact 0
        float sum = ex;
        #pragma unroll
        for (int o = 32; o; o >>= 1) sum += __shfl_xor(sum, o);
        float g = ex / sum;
        gacc += g;

        // argmax, lowest-index tie-break (softmax monotone -> matches ref)
        float bg = g; int bi = lane;
        #pragma unroll
        for (int o = 32; o; o >>= 1) {
            float og = __shfl_xor(bg, o);
            int   oi = __shfl_xor(bi, o);
            if (og > bg || (og == bg && oi < bi)) { bg = og; bi = oi; }
        }
        if (lane == 0) {
            eidx[r] = bi;
            gval[r] = bg;
            atomicAdd(&hist[bi], 1);
        }
    }
    sG[wid][lane] = gacc;
    __syncthreads();
    if (tid < NE) {
        Gslot[bid * NE + tid] = sG[0][tid] + sG[1][tid] + sG[2][tid] + sG[3][tid];
        Cslot[bid * NE + tid] = hist[tid];
    }
}

// ---------------- kernel B: 17 blocks. 0..15 = rank via histograms + direct scatter; 16 = l_aux -
__global__ __launch_bounds__(256) void finishC(const int* __restrict__ eidx, const float* __restrict__ gval,
                                               const float* __restrict__ Gslot, const int* __restrict__ Cslot,
                                               float* __restrict__ out) {
    const int bid = blockIdx.x;
    const int tid = threadIdx.x;

    if (bid == 16) {
        if (tid < NE) {
            const int e = tid;
            float Ge = 0.f; int Ce = 0;
            for (int b = 0; b < NGEMM; ++b) {
                Ge += Gslot[b * NE + e];
                Ce += Cslot[b * NE + e];
            }
            float v = Ge * (float)Ce;
            #pragma unroll
            for (int o = 32; o; o >>= 1) v += __shfl_xor(v, o);
            // l_aux = sum_e G_e*C_e / (S*S) * (E*E/num_2nd) = sum/65536
            if (e == 0) out[0] = v * (1.0f / 65536.0f);
        }
        return;
    }

    __shared__ int Cs[NGEMM * NE];    // 32 KB: per-32-row-block expert histograms
    __shared__ int Es[256];           // this block's 256 expert indices
    for (int t = tid; t < NGEMM * NE; t += 256) Cs[t] = Cslot[t];
    const int s = bid * 256 + tid;
    Es[tid] = eidx[s];
    __syncthreads();

    const int e  = Es[tid];
    const int b0 = s >> 5;            // global 32-row block index of s
    int rank = 0;
    for (int b = 0; b < b0; ++b) rank += Cs[b * NE + e];
    for (int jl = (tid & ~31); jl < tid; ++jl) rank += (Es[jl] == e);

    if (rank < CAP) {
        size_t base = 1 + (((size_t)s * NE + e) * CAP + (size_t)rank);
        out[base] = gval[s];                                  // combine
        out[base + (size_t)S_ROWS * NE * CAP] = 1.0f;         // dispatch
    }
}

extern "C" void kernel_launch(void* const* d_in, const int* in_sizes, int n_in,
                              void* d_out, int out_size, void* d_ws, size_t ws_size,
                              hipStream_t stream) {
    const float* in1 = (const float*)d_in[0];
    const float* in2 = (const float*)d_in[1];
    const float* wg1 = (const float*)d_in[2];
    const float* wg2 = (const float*)d_in[3];
    float* out = (float*)d_out;

    int*   eidx  = (int*)d_ws;                          // [4096]
    float* gv    = (float*)(eidx + S_ROWS);             // [4096]
    float* Gslot = gv + S_ROWS;                         // [128*64]
    int*   Cslot = (int*)(Gslot + NGEMM * NE);          // [128*64]

    long long n  = (long long)out_size;
    long long n4 = n >> 2;

    fusedA<<<NGEMM + NFILL, 256, 0, stream>>>(in1, wg1, in2, wg2,
                                              eidx, gv, Gslot, Cslot,
                                              (v4f*)out, n4, out, n);
    finishC<<<17, 256, 0, stream>>>(eidx, gv, Gslot, Cslot, out);
}